// Round 1
// baseline (926.970 us; speedup 1.0000x reference)
//
#include <hip/hip_runtime.h>
#include <hip/hip_bf16.h>
#include <stdint.h>

// Problem constants
#define H_ 8
#define N_ 512
#define V_ 64
#define QL_ 64
#define VH_ 512
#define B_ 32
#define S_ 512

typedef __attribute__((ext_vector_type(8))) short short8;
typedef __attribute__((ext_vector_type(4))) float floatx4;
typedef __attribute__((ext_vector_type(4))) unsigned short ushortx4;

// Native RTNE conversions (compiler emits v_cvt_pk_bf16_f32 on gfx950).
static __device__ __forceinline__ unsigned short f2bf(float x) {
    return __bfloat16_as_ushort(__float2bfloat16(x));
}
static __device__ __forceinline__ float bf2f(unsigned short u) {
    return __uint_as_float(((unsigned int)u) << 16);
}
static __device__ __forceinline__ unsigned int pack2(float lo, float hi) {
    union { __hip_bfloat162 h2; unsigned int u; } cv;
    cv.h2 = __float22bfloat162_rn(make_float2(lo, hi));
    return cv.u;
}

// ---------------- fused restage: qb cvt + hk cvt + conn sigmoid ----------------
// tasks: [0,65536) qb ; [65536,327680) hk ; [327680,851968) conn
__global__ __launch_bounds__(256) void k_prep(
    const float4* __restrict__ qb4, const float4* __restrict__ hk4,
    const float4* __restrict__ cn4, const int* __restrict__ flag,
    ushortx4* __restrict__ qo, ushortx4* __restrict__ ko, ushortx4* __restrict__ so)
{
    int i = blockIdx.x * 256 + threadIdx.x;
    if (i < 65536) {
        float4 v = qb4[i];
        ushortx4 o;
        o.x = f2bf(v.x); o.y = f2bf(v.y); o.z = f2bf(v.z); o.w = f2bf(v.w);
        qo[i] = o;
    } else if (i < 65536 + 262144) {
        int j = i - 65536;
        float4 v = hk4[j];
        ushortx4 o;
        o.x = f2bf(v.x); o.y = f2bf(v.y); o.z = f2bf(v.z); o.w = f2bf(v.w);
        ko[j] = o;
    } else {
        int j = i - (65536 + 262144);
        int f = *flag;
        float4 v = cn4[j];
        ushortx4 o;
        o.x = f2bf(f ? 1.0f / (1.0f + __expf(-v.x)) : 1.0f);
        o.y = f2bf(f ? 1.0f / (1.0f + __expf(-v.y)) : 1.0f);
        o.z = f2bf(f ? 1.0f / (1.0f + __expf(-v.z)) : 1.0f);
        o.w = f2bf(f ? 1.0f / (1.0f + __expf(-v.w)) : 1.0f);
        so[j] = o;
    }
}

// hidden_values [B][S][VH] f32 -> valst [B][H][V][S] bf16 (vals[b,h,s,v]=hv[b,s,v*8+h])
__global__ __launch_bounds__(256) void k_vtrans(const float* __restrict__ hv,
                                                unsigned short* __restrict__ vt) {
    __shared__ __align__(16) unsigned int T[256][36];
    int b = blockIdx.x, sc = blockIdx.y, half = blockIdx.z;
    int t = threadIdx.x;
    int s0 = sc * 64, vh0 = half * 256;
    int s2 = t & 31;
    for (int rep = 0; rep < 8; ++rep) {
        int vh4 = rep * 8 + (t >> 5);
        const float* g = &hv[((size_t)(b * 512 + s0 + 2 * s2)) * 512 + vh0 + vh4 * 4];
        float4 lo = *(const float4*)g;
        float4 hi = *(const float4*)(g + 512);
        T[vh4 * 4 + 0][s2] = pack2(lo.x, hi.x);
        T[vh4 * 4 + 1][s2] = pack2(lo.y, hi.y);
        T[vh4 * 4 + 2][s2] = pack2(lo.z, hi.z);
        T[vh4 * 4 + 3][s2] = pack2(lo.w, hi.w);
    }
    __syncthreads();
    for (int rep = 0; rep < 8; ++rep) {
        int row = rep * 32 + (t >> 3);
        int m = t & 7;
        uint4 d = *(const uint4*)&T[row][m * 4];
        int h = row & 7, v = half * 32 + (row >> 3);
        *(uint4*)&vt[((size_t)((b * 8 + h) * 64 + v)) * 512 + s0 + m * 8] = d;
    }
}

// ---------------- attention ----------------
// grid (x=b 32, y=h*8+nt 64); block 256 = 4 waves; wave w owns n-rows [n0+16w, n0+16w+16)
// Pipelined: chunk ch+1 (K,V,Sg) prefetched into registers during chunk ch compute.
__global__ __launch_bounds__(256, 2) void k_attn(
    const unsigned short* __restrict__ qb,   // [H*N][64] bf16
    const unsigned short* __restrict__ kb,   // [B][S][64] bf16
    const unsigned short* __restrict__ vt,   // [B][H][V][S] bf16
    const unsigned short* __restrict__ sg,   // [H][N][S] bf16
    unsigned short* __restrict__ ao)         // [B][H][N][V] bf16
{
    __shared__ __align__(16) unsigned short Ks[128][72];
    __shared__ __align__(16) unsigned short Vs[64][136];
    __shared__ __align__(16) unsigned short Ps[64][136];
    __shared__ __align__(16) unsigned short Sg[64][136];

    int b = blockIdx.x;
    int h = blockIdx.y >> 3;
    int nt = blockIdx.y & 7;
    int n0 = nt * 64;
    int t = threadIdx.x;
    int w = t >> 6, l = t & 63;
    int c = l & 15, q = l >> 4;

    const unsigned short* kbase = &kb[(size_t)b * (512 * 64)];
    const unsigned short* vbase = &vt[((size_t)(b * 8 + h)) * (64 * 512)];
    const unsigned short* sbase = &sg[((size_t)(h * 512 + n0)) * 512];

    // Q A-fragments straight from global (one-time; L2-resident)
    const unsigned short* qrow = &qb[((size_t)(h * 512 + n0 + w * 16 + c)) * 64];
    short8 qa0 = *(const short8*)&qrow[q * 8];
    short8 qa1 = *(const short8*)&qrow[32 + q * 8];

    uint4 pk[4], pv[4], ps[4];
    auto loadc = [&](int s0) {
        #pragma unroll
        for (int rep = 0; rep < 4; ++rep) {
            int task = rep * 256 + t;
            int r1 = task >> 3, s1 = task & 7;       // K: 128 rows x 8 segs
            pk[rep] = *(const uint4*)&kbase[(size_t)(s0 + r1) * 64 + s1 * 8];
            int r2 = task >> 4, s2 = task & 15;      // V,Sg: 64 rows x 16 segs
            pv[rep] = *(const uint4*)&vbase[(size_t)r2 * 512 + s0 + s2 * 8];
            ps[rep] = *(const uint4*)&sbase[(size_t)r2 * 512 + s0 + s2 * 8];
        }
    };
    auto writec = [&]() {
        #pragma unroll
        for (int rep = 0; rep < 4; ++rep) {
            int task = rep * 256 + t;
            int r1 = task >> 3, s1 = task & 7;
            *(uint4*)&Ks[r1][s1 * 8] = pk[rep];
            int r2 = task >> 4, s2 = task & 15;
            *(uint4*)&Vs[r2][s2 * 8] = pv[rep];
            *(uint4*)&Sg[r2][s2 * 8] = ps[rep];
        }
    };

    loadc(0);
    writec();
    __syncthreads();

    floatx4 zero = {0.0f, 0.0f, 0.0f, 0.0f};
    floatx4 oacc[4];
    #pragma unroll
    for (int i = 0; i < 4; ++i) oacc[i] = zero;
    float rsum[4] = {0.f, 0.f, 0.f, 0.f};

    for (int ch = 0; ch < 4; ++ch) {
        if (ch < 3) loadc((ch + 1) * 128);   // in flight across whole chunk compute

        // QK^T for this wave's 16 n-rows over 128 s
        floatx4 sacc[8];
        #pragma unroll
        for (int st = 0; st < 8; ++st) {
            short8 kb0 = *(const short8*)&Ks[st * 16 + c][q * 8];
            short8 kb1 = *(const short8*)&Ks[st * 16 + c][32 + q * 8];
            floatx4 a = zero;
            a = __builtin_amdgcn_mfma_f32_16x16x32_bf16(qa0, kb0, a, 0, 0, 0);
            a = __builtin_amdgcn_mfma_f32_16x16x32_bf16(qa1, kb1, a, 0, 0, 0);
            sacc[st] = a;
        }
        // e = exp(score/8)*sig(c) with sig from LDS; accumulate row sums; write P
        float esum[4] = {0.f, 0.f, 0.f, 0.f};
        #pragma unroll
        for (int st = 0; st < 8; ++st) {
            #pragma unroll
            for (int r = 0; r < 4; ++r) {
                int nl = w * 16 + q * 4 + r;
                float e = __expf(sacc[st][r] * 0.125f) * bf2f(Sg[nl][st * 16 + c]);
                esum[r] += e;
                Ps[nl][st * 16 + c] = f2bf(e);
            }
        }
        #pragma unroll
        for (int m = 1; m <= 8; m <<= 1) {
            #pragma unroll
            for (int r = 0; r < 4; ++r) esum[r] += __shfl_xor(esum[r], m, 64);
        }
        #pragma unroll
        for (int r = 0; r < 4; ++r) rsum[r] += esum[r];
        __syncthreads();   // Ps visible; Ks/Sg reads done

        // P @ V accumulate
        #pragma unroll
        for (int k2 = 0; k2 < 4; ++k2) {
            short8 pa = *(const short8*)&Ps[w * 16 + c][k2 * 32 + q * 8];
            #pragma unroll
            for (int vtile = 0; vtile < 4; ++vtile) {
                short8 vb = *(const short8*)&Vs[vtile * 16 + c][k2 * 32 + q * 8];
                oacc[vtile] = __builtin_amdgcn_mfma_f32_16x16x32_bf16(pa, vb, oacc[vtile], 0, 0, 0);
            }
        }
        __syncthreads();   // Vs/Ps reads done
        if (ch < 3) {
            writec();      // stage next chunk from prefetched regs
            __syncthreads();
        }
    }

    #pragma unroll
    for (int r = 0; r < 4; ++r) {
        float rcp = 1.0f / rsum[r];
        int n_g = n0 + w * 16 + q * 4 + r;
        #pragma unroll
        for (int vtile = 0; vtile < 4; ++vtile) {
            float o = oacc[vtile][r] * rcp;
            ao[((size_t)((b * 8 + h) * 512 + n_g)) * 64 + vtile * 16 + c] = f2bf(o);
        }
    }
}

// ---------------- layernorm ----------------
__global__ __launch_bounds__(256) void k_ln(
    const unsigned short* __restrict__ ao,
    const float* __restrict__ gamma, const float* __restrict__ beta,
    unsigned short* __restrict__ xln)
{
    __shared__ __align__(16) unsigned short xrow[4][512];
    __shared__ float gs[512], bs[512];
    int t = threadIdx.x;
    for (int i = t; i < 512; i += 256) { gs[i] = gamma[i]; bs[i] = beta[i]; }
    __syncthreads();
    int w = t >> 6, l = t & 63;
    int idx = blockIdx.x * 4 + w;
    int b = idx >> 9, n = idx & 511;
    int hh = l >> 3, vb = (l & 7) * 8;
    uint4 raw = *(const uint4*)&ao[((size_t)((b * 8 + hh) * 512 + n)) * 64 + vb];
    unsigned int u[4] = {raw.x, raw.y, raw.z, raw.w};
    float x[8];
    float sum = 0.f, ss = 0.f;
    for (int j = 0; j < 4; ++j) {
        x[2 * j]     = bf2f((unsigned short)(u[j] & 0xffffu));
        x[2 * j + 1] = bf2f((unsigned short)(u[j] >> 16));
    }
    for (int j = 0; j < 8; ++j) { sum += x[j]; ss += x[j] * x[j]; }
    for (int m = 1; m <= 32; m <<= 1) {
        sum += __shfl_xor(sum, m, 64);
        ss  += __shfl_xor(ss, m, 64);
    }
    float mu = sum * (1.0f / 512.0f);
    float var = ss * (1.0f / 512.0f) - mu * mu;
    float rstd = rsqrtf(var + 1e-12f);
    for (int j = 0; j < 8; ++j) {
        int vh = (vb + j) * 8 + hh;
        float y = (x[j] - mu) * rstd * gs[vh] + bs[vh];
        xrow[w][vh] = f2bf(y);
    }
    __syncthreads();
    uint4 outv = *(const uint4*)&xrow[w][l * 8];
    *(uint4*)&xln[((size_t)(n * 32 + b)) * 512 + l * 8] = outv;
}

// ---------------- per-neuron GEMM ----------------
// Block = (neuron n, o-slab of OSUB cols). Double-buffered LDS, single barrier/kc,
// W prefetch for kc+1 issued before the barrier (loads stay in flight across it).
// T row stride 20 dwords (80 B, 16B-aligned): bank starts {0,20,8,28,16,4,24,12}
// -> B-frag ds_read_b128 is <=2-way (free) instead of 8-way.
template<int O, int OSUB>
__global__ __launch_bounds__(256, 4) void k_gemm(
    const unsigned short* __restrict__ xln,  // [N][B][VH] bf16
    const float* __restrict__ Wg,            // [N][512][O] f32
    const float* __restrict__ bias,          // [N][O] f32
    float* __restrict__ out)                 // [B][N][O] f32
{
    constexpr int REPS = OSUB / 64;
    constexpr int OT = OSUB / 64;
    __shared__ __align__(16) unsigned int T[2][OSUB][20];
    int n = blockIdx.x;
    int o0 = blockIdx.y * OSUB;
    int t = threadIdx.x, w = t >> 6, l = t & 63;
    int c = l & 15, q = l >> 4;
    int k2l = t & 15;
    int og = t >> 4;

    floatx4 zero = {0.0f, 0.0f, 0.0f, 0.0f};
    floatx4 acc[2][OT];
    #pragma unroll
    for (int mt = 0; mt < 2; ++mt)
        #pragma unroll
        for (int ot = 0; ot < OT; ++ot) acc[mt][ot] = zero;

    const unsigned short* a0p = &xln[((size_t)(n * 32 + c)) * 512];
    const unsigned short* a1p = &xln[((size_t)(n * 32 + 16 + c)) * 512];
    const float* wbase = Wg + (size_t)n * 512 * O + o0;

    float4 plo[REPS], phi[REPS];
    short8 a0r, a1r;
    #pragma unroll
    for (int rep = 0; rep < REPS; ++rep) {
        const float* g0 = wbase + (size_t)(2 * k2l) * O + (rep * 16 + og) * 4;
        plo[rep] = *(const float4*)g0;
        phi[rep] = *(const float4*)(g0 + O);
    }
    a0r = *(const short8*)&a0p[q * 8];
    a1r = *(const short8*)&a1p[q * 8];

    for (int kc = 0; kc < 16; ++kc) {
        int buf = kc & 1;
        short8 a0 = a0r, a1 = a1r;
        #pragma unroll
        for (int rep = 0; rep < REPS; ++rep) {
            int o4 = rep * 16 + og;
            T[buf][o4 * 4 + 0][k2l] = pack2(plo[rep].x, phi[rep].x);
            T[buf][o4 * 4 + 1][k2l] = pack2(plo[rep].y, phi[rep].y);
            T[buf][o4 * 4 + 2][k2l] = pack2(plo[rep].z, phi[rep].z);
            T[buf][o4 * 4 + 3][k2l] = pack2(plo[rep].w, phi[rep].w);
            if (kc < 15) {   // reissue this rep's loads for kc+1 (regs just freed)
                const float* g0 = wbase + (size_t)((kc + 1) * 32 + 2 * k2l) * O + o4 * 4;
                plo[rep] = *(const float4*)g0;
                phi[rep] = *(const float4*)(g0 + O);
            }
        }
        if (kc < 15) {
            a0r = *(const short8*)&a0p[(kc + 1) * 32 + q * 8];
            a1r = *(const short8*)&a1p[(kc + 1) * 32 + q * 8];
        }
        __syncthreads();   // T[buf] visible; also guards next iter's write of T[buf^1]
        #pragma unroll
        for (int ot = 0; ot < OT; ++ot) {
            short8 bw = *(const short8*)&T[buf][(w * OT + ot) * 16 + c][q * 4];
            acc[0][ot] = __builtin_amdgcn_mfma_f32_16x16x32_bf16(a0, bw, acc[0][ot], 0, 0, 0);
            acc[1][ot] = __builtin_amdgcn_mfma_f32_16x16x32_bf16(a1, bw, acc[1][ot], 0, 0, 0);
        }
    }

    #pragma unroll
    for (int ot = 0; ot < OT; ++ot) {
        int oc = (w * OT + ot) * 16 + c;
        float bv = bias[(size_t)n * O + o0 + oc];
        #pragma unroll
        for (int mt = 0; mt < 2; ++mt) {
            #pragma unroll
            for (int r = 0; r < 4; ++r) {
                int brow = mt * 16 + q * 4 + r;
                out[((size_t)(brow * 512 + n)) * O + o0 + oc] = acc[mt][ot][r] + bv;
            }
        }
    }
}

extern "C" void kernel_launch(void* const* d_in, const int* in_sizes, int n_in,
                              void* d_out, int out_size, void* d_ws, size_t ws_size,
                              hipStream_t stream) {
    const float* hk    = (const float*)d_in[0];   // hidden_keys [32][512][64]
    const float* hv    = (const float*)d_in[1];   // hidden_values [32][512][512]
    const float* qb    = (const float*)d_in[2];   // query_bank [4096][64]
    const float* conn  = (const float*)d_in[3];   // connectivity [1][8][512][512]
    const float* gamma = (const float*)d_in[4];
    const float* beta  = (const float*)d_in[5];
    const float* kw    = (const float*)d_in[6];   // keys_w [512][512][64]
    const float* kbias = (const float*)d_in[7];   // keys_b [512][64]
    const float* vw    = (const float*)d_in[8];   // values_w [512][512][512]
    const float* vbias = (const float*)d_in[9];   // values_b [512][512]
    const int* flag    = (const int*)d_in[10];

    char* ws = (char*)d_ws;
    unsigned short* vts = (unsigned short*)ws;                      // 16 MB [B][H][V][S]
    unsigned short* sgc = (unsigned short*)(ws + (16u << 20));      // 4 MB  [H][N][S]
    unsigned short* kbf = (unsigned short*)(ws + (20u << 20));      // 2 MB  [B][S][64]
    unsigned short* qbf = (unsigned short*)(ws + (22u << 20));      // 0.5MB [H*N][64]
    unsigned short* aow = (unsigned short*)(ws + (23u << 20));      // 16 MB [B][H][N][V]
    unsigned short* xln = (unsigned short*)ws;                      // 16 MB [N][B][VH] (reuses vts)

    k_prep<<<3328, 256, 0, stream>>>((const float4*)qb, (const float4*)hk,
                                     (const float4*)conn, flag,
                                     (ushortx4*)qbf, (ushortx4*)kbf, (ushortx4*)sgc);
    k_vtrans<<<dim3(32, 8, 2), 256, 0, stream>>>(hv, vts);
    k_attn<<<dim3(32, 64), 256, 0, stream>>>(qbf, kbf, vts, sgc, aow);
    k_ln<<<4096, 256, 0, stream>>>(aow, gamma, beta, xln);
    k_gemm<64, 64><<<dim3(512, 1), 256, 0, stream>>>(xln, kw, kbias, (float*)d_out);
    k_gemm<512, 128><<<dim3(512, 4), 256, 0, stream>>>(xln, vw, vbias, (float*)d_out + 1048576);
}

// Round 2
// 878.653 us; speedup vs baseline: 1.0550x; 1.0550x over previous
//
#include <hip/hip_runtime.h>
#include <hip/hip_bf16.h>
#include <stdint.h>

// Problem constants
#define H_ 8
#define N_ 512
#define V_ 64
#define QL_ 64
#define VH_ 512
#define B_ 32
#define S_ 512

typedef __attribute__((ext_vector_type(8))) short short8;
typedef __attribute__((ext_vector_type(4))) float floatx4;
typedef __attribute__((ext_vector_type(4))) unsigned short ushortx4;

// Native RTNE conversions (compiler emits v_cvt_pk_bf16_f32 on gfx950).
static __device__ __forceinline__ unsigned short f2bf(float x) {
    return __bfloat16_as_ushort(__float2bfloat16(x));
}
static __device__ __forceinline__ float bf2f(unsigned short u) {
    return __uint_as_float(((unsigned int)u) << 16);
}
static __device__ __forceinline__ unsigned int pack2(float lo, float hi) {
    union { __hip_bfloat162 h2; unsigned int u; } cv;
    cv.h2 = __float22bfloat162_rn(make_float2(lo, hi));
    return cv.u;
}

// ---------------- fused restage: qb cvt + hk cvt + conn sigmoid ----------------
// tasks: [0,65536) qb ; [65536,327680) hk ; [327680,851968) conn
__global__ __launch_bounds__(256) void k_prep(
    const float4* __restrict__ qb4, const float4* __restrict__ hk4,
    const float4* __restrict__ cn4, const int* __restrict__ flag,
    ushortx4* __restrict__ qo, ushortx4* __restrict__ ko, ushortx4* __restrict__ so)
{
    int i = blockIdx.x * 256 + threadIdx.x;
    if (i < 65536) {
        float4 v = qb4[i];
        ushortx4 o;
        o.x = f2bf(v.x); o.y = f2bf(v.y); o.z = f2bf(v.z); o.w = f2bf(v.w);
        qo[i] = o;
    } else if (i < 65536 + 262144) {
        int j = i - 65536;
        float4 v = hk4[j];
        ushortx4 o;
        o.x = f2bf(v.x); o.y = f2bf(v.y); o.z = f2bf(v.z); o.w = f2bf(v.w);
        ko[j] = o;
    } else {
        int j = i - (65536 + 262144);
        int f = *flag;
        float4 v = cn4[j];
        ushortx4 o;
        o.x = f2bf(f ? 1.0f / (1.0f + __expf(-v.x)) : 1.0f);
        o.y = f2bf(f ? 1.0f / (1.0f + __expf(-v.y)) : 1.0f);
        o.z = f2bf(f ? 1.0f / (1.0f + __expf(-v.z)) : 1.0f);
        o.w = f2bf(f ? 1.0f / (1.0f + __expf(-v.w)) : 1.0f);
        so[j] = o;
    }
}

// hidden_values [B][S][VH] f32 -> valst [B][H][V][S] bf16 (vals[b,h,s,v]=hv[b,s,v*8+h])
__global__ __launch_bounds__(256) void k_vtrans(const float* __restrict__ hv,
                                                unsigned short* __restrict__ vt) {
    __shared__ __align__(16) unsigned int T[256][36];
    int b = blockIdx.x, sc = blockIdx.y, half = blockIdx.z;
    int t = threadIdx.x;
    int s0 = sc * 64, vh0 = half * 256;
    int s2 = t & 31;
    for (int rep = 0; rep < 8; ++rep) {
        int vh4 = rep * 8 + (t >> 5);
        const float* g = &hv[((size_t)(b * 512 + s0 + 2 * s2)) * 512 + vh0 + vh4 * 4];
        float4 lo = *(const float4*)g;
        float4 hi = *(const float4*)(g + 512);
        T[vh4 * 4 + 0][s2] = pack2(lo.x, hi.x);
        T[vh4 * 4 + 1][s2] = pack2(lo.y, hi.y);
        T[vh4 * 4 + 2][s2] = pack2(lo.z, hi.z);
        T[vh4 * 4 + 3][s2] = pack2(lo.w, hi.w);
    }
    __syncthreads();
    for (int rep = 0; rep < 8; ++rep) {
        int row = rep * 32 + (t >> 3);
        int m = t & 7;
        uint4 d = *(const uint4*)&T[row][m * 4];
        int h = row & 7, v = half * 32 + (row >> 3);
        *(uint4*)&vt[((size_t)((b * 8 + h) * 64 + v)) * 512 + s0 + m * 8] = d;
    }
}

// ---------------- attention ----------------
// grid (x=b 32, y=h*8+nt 64); block 256 = 4 waves; wave w owns n-rows [n0+16w, n0+16w+16)
// Round-0 proven structure; Qs LDS tile dropped (Q frags direct from global, L3-resident)
// -> LDS 52 KB -> 3 blocks/CU (12 waves/CU) instead of 2.
__global__ __launch_bounds__(256) void k_attn(
    const unsigned short* __restrict__ qb,   // [H*N][64] bf16
    const unsigned short* __restrict__ kb,   // [B][S][64] bf16
    const unsigned short* __restrict__ vt,   // [B][H][V][S] bf16
    const unsigned short* __restrict__ sg,   // [H][N][S] bf16
    unsigned short* __restrict__ ao)         // [B][H][N][V] bf16
{
    __shared__ __align__(16) unsigned short Ks[128][72];
    __shared__ __align__(16) unsigned short Vs[64][136];
    __shared__ __align__(16) unsigned short Ps[64][136];

    int b = blockIdx.x;
    int h = blockIdx.y >> 3;
    int nt = blockIdx.y & 7;
    int n0 = nt * 64;
    int t = threadIdx.x;
    int w = t >> 6, l = t & 63;
    int c = l & 15, q = l >> 4;

    // Q A-fragments straight from global (A[m=l&15][k=q*8+j], k split in two 32-steps)
    const unsigned short* qrow = &qb[((size_t)(h * 512 + n0 + w * 16 + c)) * 64];
    short8 qa0 = *(const short8*)&qrow[q * 8];
    short8 qa1 = *(const short8*)&qrow[32 + q * 8];

    floatx4 zero = {0.0f, 0.0f, 0.0f, 0.0f};
    floatx4 oacc[4];
    for (int i = 0; i < 4; ++i) oacc[i] = zero;
    float rsum[4] = {0.f, 0.f, 0.f, 0.f};

    for (int ch = 0; ch < 4; ++ch) {
        int s0 = ch * 128;
        // stage K chunk: 128 rows x 128 B = 1024 uint4
        for (int rep = 0; rep < 4; ++rep) {
            int task = rep * 256 + t;
            int row = task >> 3, seg = task & 7;
            *(uint4*)&Ks[row][seg * 8] =
                *(const uint4*)&kb[((size_t)(b * 512 + s0 + row)) * 64 + seg * 8];
        }
        // stage V chunk: 64 v-rows x 256 B = 1024 uint4
        for (int rep = 0; rep < 4; ++rep) {
            int task = rep * 256 + t;
            int row = task >> 4, seg = task & 15;
            *(uint4*)&Vs[row][seg * 8] =
                *(const uint4*)&vt[((size_t)((b * 8 + h) * 64 + row)) * 512 + s0 + seg * 8];
        }
        __syncthreads();

        // QK^T for this wave's 16 n-rows over 128 s
        floatx4 sacc[8];
        for (int st = 0; st < 8; ++st) {
            short8 kb0 = *(const short8*)&Ks[st * 16 + c][q * 8];
            short8 kb1 = *(const short8*)&Ks[st * 16 + c][32 + q * 8];
            floatx4 acc = zero;
            acc = __builtin_amdgcn_mfma_f32_16x16x32_bf16(qa0, kb0, acc, 0, 0, 0);
            acc = __builtin_amdgcn_mfma_f32_16x16x32_bf16(qa1, kb1, acc, 0, 0, 0);
            sacc[st] = acc;
        }
        // e = exp(score/8)*sig(c); accumulate row sums; write P chunk (bf16)
        float esum[4] = {0.f, 0.f, 0.f, 0.f};
        for (int st = 0; st < 8; ++st) {
            int s_g = s0 + st * 16 + c;
            for (int r = 0; r < 4; ++r) {
                int nl = w * 16 + q * 4 + r;           // C-layout: row=(l>>4)*4+r
                float scv = sacc[st][r] * 0.125f;
                float sgv = bf2f(sg[((size_t)(h * 512 + n0 + nl)) * 512 + s_g]);
                float e = __expf(scv) * sgv;
                esum[r] += e;
                Ps[nl][st * 16 + c] = f2bf(e);
            }
        }
        // butterfly over the 16 col-lanes (bits 0-3) -> full row sums of this chunk
        for (int m = 1; m <= 8; m <<= 1)
            for (int r = 0; r < 4; ++r) esum[r] += __shfl_xor(esum[r], m, 64);
        for (int r = 0; r < 4; ++r) rsum[r] += esum[r];
        __syncthreads();   // P visible

        // P @ V accumulate (A from own P rows, B from Vs)
        for (int k2 = 0; k2 < 4; ++k2) {
            short8 pa = *(const short8*)&Ps[w * 16 + c][k2 * 32 + q * 8];
            for (int vtile = 0; vtile < 4; ++vtile) {
                short8 vb = *(const short8*)&Vs[vtile * 16 + c][k2 * 32 + q * 8];
                oacc[vtile] = __builtin_amdgcn_mfma_f32_16x16x32_bf16(pa, vb, oacc[vtile], 0, 0, 0);
            }
        }
        __syncthreads();   // before restaging K/V/P next chunk
    }

    // divide by row sums (same lane holds matching rows) and store bf16
    for (int r = 0; r < 4; ++r) {
        float rcp = 1.0f / rsum[r];
        int n_g = n0 + w * 16 + q * 4 + r;
        for (int vtile = 0; vtile < 4; ++vtile) {
            float o = oacc[vtile][r] * rcp;
            ao[((size_t)((b * 8 + h) * 512 + n_g)) * 64 + vtile * 16 + c] = f2bf(o);
        }
    }
}

// ---------------- layernorm ----------------
__global__ __launch_bounds__(256) void k_ln(
    const unsigned short* __restrict__ ao,
    const float* __restrict__ gamma, const float* __restrict__ beta,
    unsigned short* __restrict__ xln)
{
    __shared__ __align__(16) unsigned short xrow[4][512];
    __shared__ float gs[512], bs[512];
    int t = threadIdx.x;
    for (int i = t; i < 512; i += 256) { gs[i] = gamma[i]; bs[i] = beta[i]; }
    __syncthreads();
    int w = t >> 6, l = t & 63;
    int idx = blockIdx.x * 4 + w;
    int b = idx >> 9, n = idx & 511;
    int hh = l >> 3, vb = (l & 7) * 8;
    uint4 raw = *(const uint4*)&ao[((size_t)((b * 8 + hh) * 512 + n)) * 64 + vb];
    unsigned int u[4] = {raw.x, raw.y, raw.z, raw.w};
    float x[8];
    float sum = 0.f, ss = 0.f;
    for (int j = 0; j < 4; ++j) {
        x[2 * j]     = bf2f((unsigned short)(u[j] & 0xffffu));
        x[2 * j + 1] = bf2f((unsigned short)(u[j] >> 16));
    }
    for (int j = 0; j < 8; ++j) { sum += x[j]; ss += x[j] * x[j]; }
    for (int m = 1; m <= 32; m <<= 1) {
        sum += __shfl_xor(sum, m, 64);
        ss  += __shfl_xor(ss, m, 64);
    }
    float mu = sum * (1.0f / 512.0f);
    float var = ss * (1.0f / 512.0f) - mu * mu;
    float rstd = rsqrtf(var + 1e-12f);
    for (int j = 0; j < 8; ++j) {
        int vh = (vb + j) * 8 + hh;
        float y = (x[j] - mu) * rstd * gs[vh] + bs[vh];
        xrow[w][vh] = f2bf(y);
    }
    __syncthreads();
    uint4 outv = *(const uint4*)&xrow[w][l * 8];
    *(uint4*)&xln[((size_t)(n * 32 + b)) * 512 + l * 8] = outv;
}

// ---------------- per-neuron GEMM (round-0 proven body) ----------------
// W staged to LDS as pair-packed dwords T[o][k2]; rot-staggered writes keep stores
// ~conflict-free; B-fragment = one aligned ds_read_b128. Two barriers per kc; the
// per-round BW-serialization (~12.5k cyc) >> HBM latency, so this is BW-bound as-is.
template<int O>
static __device__ __forceinline__ void gemm_body(
    const unsigned short* __restrict__ xln,  // [N][B][VH] bf16
    const float* __restrict__ Wg,            // [N][512][O] f32
    const float* __restrict__ bias,          // [N][O] f32
    float* __restrict__ out,                 // [B][N][O] f32
    int n, int t, unsigned int (*T)[16])
{
    constexpr int OT = O / 64;
    constexpr int REPS = O / 64;
    int w = t >> 6, l = t & 63;
    int c = l & 15, q = l >> 4;
    int k2l = t & 15;
    int rot = t >> 4;

    floatx4 zero = {0.0f, 0.0f, 0.0f, 0.0f};
    floatx4 acc[2][OT];
    #pragma unroll
    for (int mt = 0; mt < 2; ++mt)
        #pragma unroll
        for (int ot = 0; ot < OT; ++ot) acc[mt][ot] = zero;

    const unsigned short* a0p = &xln[((size_t)(n * 32 + c)) * 512];
    const unsigned short* a1p = &xln[((size_t)(n * 32 + 16 + c)) * 512];

    for (int kc = 0; kc < 16; ++kc) {
        #pragma unroll
        for (int rep = 0; rep < REPS; ++rep) {
            int o4 = rep * 16 + (t >> 4);
            const float* g0 = &Wg[(((size_t)n * 512) + kc * 32 + 2 * k2l) * O + o4 * 4];
            float4 lo = *(const float4*)g0;
            float4 hi = *(const float4*)(g0 + O);
            unsigned int d[4];
            d[0] = pack2(lo.x, hi.x);
            d[1] = pack2(lo.y, hi.y);
            d[2] = pack2(lo.z, hi.z);
            d[3] = pack2(lo.w, hi.w);
            #pragma unroll
            for (int i = 0; i < 4; ++i) {
                int j = (rot + i) & 3;
                T[o4 * 4 + j][k2l] = d[j];
            }
        }
        __syncthreads();
        short8 a0 = *(const short8*)&a0p[kc * 32 + q * 8];
        short8 a1 = *(const short8*)&a1p[kc * 32 + q * 8];
        #pragma unroll
        for (int ot = 0; ot < OT; ++ot) {
            short8 bw = *(const short8*)&T[(w * OT + ot) * 16 + c][q * 4];
            acc[0][ot] = __builtin_amdgcn_mfma_f32_16x16x32_bf16(a0, bw, acc[0][ot], 0, 0, 0);
            acc[1][ot] = __builtin_amdgcn_mfma_f32_16x16x32_bf16(a1, bw, acc[1][ot], 0, 0, 0);
        }
        __syncthreads();
    }
    #pragma unroll
    for (int ot = 0; ot < OT; ++ot) {
        int o = (w * OT + ot) * 16 + c;
        float bv = bias[(size_t)n * O + o];
        #pragma unroll
        for (int mt = 0; mt < 2; ++mt) {
            #pragma unroll
            for (int r = 0; r < 4; ++r) {
                int brow = mt * 16 + q * 4 + r;
                out[((size_t)(brow * 512 + n)) * O + o] = acc[mt][ot][r] + bv;
            }
        }
    }
}

// Fused launch: x<512 -> values GEMM (heavy, dispatched first so keys blocks
// backfill CUs under the 512 MB stream); x>=512 -> keys GEMM.
__global__ __launch_bounds__(256) void k_gemm_fused(
    const unsigned short* __restrict__ xln,
    const float* __restrict__ vw, const float* __restrict__ vbias,
    const float* __restrict__ kw, const float* __restrict__ kbias,
    float* __restrict__ out)
{
    __shared__ __align__(16) unsigned int T[512][16];
    int t = threadIdx.x;
    if (blockIdx.x < 512) {
        gemm_body<512>(xln, vw, vbias, out + 1048576, blockIdx.x, t, T);
    } else {
        gemm_body<64>(xln, kw, kbias, out, blockIdx.x - 512, t, T);
    }
}

extern "C" void kernel_launch(void* const* d_in, const int* in_sizes, int n_in,
                              void* d_out, int out_size, void* d_ws, size_t ws_size,
                              hipStream_t stream) {
    const float* hk    = (const float*)d_in[0];   // hidden_keys [32][512][64]
    const float* hv    = (const float*)d_in[1];   // hidden_values [32][512][512]
    const float* qb    = (const float*)d_in[2];   // query_bank [4096][64]
    const float* conn  = (const float*)d_in[3];   // connectivity [1][8][512][512]
    const float* gamma = (const float*)d_in[4];
    const float* beta  = (const float*)d_in[5];
    const float* kw    = (const float*)d_in[6];   // keys_w [512][512][64]
    const float* kbias = (const float*)d_in[7];   // keys_b [512][64]
    const float* vw    = (const float*)d_in[8];   // values_w [512][512][512]
    const float* vbias = (const float*)d_in[9];   // values_b [512][512]
    const int* flag    = (const int*)d_in[10];

    char* ws = (char*)d_ws;
    unsigned short* vts = (unsigned short*)ws;                      // 16 MB [B][H][V][S]
    unsigned short* sgc = (unsigned short*)(ws + (16u << 20));      // 4 MB  [H][N][S]
    unsigned short* kbf = (unsigned short*)(ws + (20u << 20));      // 2 MB  [B][S][64]
    unsigned short* qbf = (unsigned short*)(ws + (22u << 20));      // 0.5MB [H*N][64]
    unsigned short* aow = (unsigned short*)(ws + (23u << 20));      // 16 MB [B][H][N][V]
    unsigned short* xln = (unsigned short*)ws;                      // 16 MB [N][B][VH] (reuses vts)

    k_prep<<<3328, 256, 0, stream>>>((const float4*)qb, (const float4*)hk,
                                     (const float4*)conn, flag,
                                     (ushortx4*)qbf, (ushortx4*)kbf, (ushortx4*)sgc);
    k_vtrans<<<dim3(32, 8, 2), 256, 0, stream>>>(hv, vts);
    k_attn<<<dim3(32, 64), 256, 0, stream>>>(qbf, kbf, vts, sgc, aow);
    k_ln<<<4096, 256, 0, stream>>>(aow, gamma, beta, xln);
    k_gemm_fused<<<1024, 256, 0, stream>>>(xln, vw, vbias, kw, kbias, (float*)d_out);
}